// Round 4
// baseline (125.982 us; speedup 1.0000x reference)
//
#include <hip/hip_runtime.h>
#include <stdint.h>

// LocalAggregation (PointNet++ SA layer, B=4 N=4096 C=32 K=32, 35->64->64)
//
// 5-kernel pipeline (was 8):
//  K1 bq_prep : blocks [0,1024): ball query -> idx[b][n][32]
//               block 1024: W1t transpose, W2 MFMA-frag pack, zero part1b/part2b
//  K2 uq      : u = W1[:,3:]x + W1[:,:3]p ; q = W1[:,:3]p   (y1 = u[j]-q[n])
//  K3 bn1     : per-channel sum/sumsq of y1; block-reduce -> atomicAdd part1b[128][8]
//  K4 stage2  : per block: a1c1 from part1b (redundant, tiny); LDS-free MFMA conv2:
//               each lane builds its A-frag (sample=l&15, ch=(l>>4)*8+e) straight from
//               the u-gather, h in regs; per-(n,o) max/min over k; BN2 partials ->
//               atomicAdd part2b[128][8]. XCD-swizzled blocks.
//  K5 out     : a2c2 from part2b (redundant, tiny); 64x64 LDS transpose, coalesced.

#define R2 0.01f
#define INVM (1.0f / 524288.0f)

typedef __bf16 bf16x8 __attribute__((ext_vector_type(8)));
typedef float f32x4 __attribute__((ext_vector_type(4)));

__device__ __forceinline__ uint32_t pack_bf16(float a, float b) {
  uint32_t ua = __float_as_uint(a), ub = __float_as_uint(b);
  ua += 0x7fffu + ((ua >> 16) & 1u);
  ub += 0x7fffu + ((ub >> 16) & 1u);
  return (ua >> 16) | (ub & 0xffff0000u);
}

// ---------------- K1: ball query + prep ----------------
__global__ __launch_bounds__(1024) void k_bq_prep(const float* __restrict__ p,
                                                  int* __restrict__ idx,
                                                  const float* __restrict__ W1,
                                                  const float* __restrict__ W2,
                                                  float* __restrict__ W1t,
                                                  uint32_t* __restrict__ w2frag,
                                                  float* __restrict__ part1b,
                                                  float* __restrict__ part2b) {
  __shared__ float px[4096], py[4096], pz[4096];
  if (blockIdx.x >= 1024) {   // prep block
    const int t = threadIdx.x;
    for (int tt = t; tt < 2240; tt += 1024) {
      const int o = tt / 35, c = tt - o * 35;
      W1t[(c << 6) + o] = W1[tt];
    }
    for (int tt = t; tt < 2048; tt += 1024) {
      const int e2 = tt & 3, lane = (tt >> 2) & 63, frag = tt >> 8;
      const int kt = frag >> 2, ot = frag & 3;
      const int c0 = kt * 32 + ((lane >> 4) << 3) + e2 * 2;
      const int o = ot * 16 + (lane & 15);
      w2frag[tt] = pack_bf16(W2[(o << 6) + c0], W2[(o << 6) + c0 + 1]);
    }
    part1b[t] = 0.f;   // 128*8 = 1024 floats each
    part2b[t] = 0.f;
    return;
  }
  const int b = blockIdx.x >> 8;             // 256 blocks per batch
  const int nb = (blockIdx.x & 255) << 4;    // 16 queries per block (1 per wave)
  const float* pb = p + b * 12288;
  for (int i = threadIdx.x; i < 4096; i += 1024) {
    px[i] = pb[3 * i]; py[i] = pb[3 * i + 1]; pz[i] = pb[3 * i + 2];
  }
  __syncthreads();
  const int wv = threadIdx.x >> 6, lane = threadIdx.x & 63;
  const int n = nb + wv;
  const float qx = px[n], qy = py[n], qz = pz[n];
  int* row = idx + (((b << 12) + n) << 5);
  int cnt = 0, first = 0;
  for (int jb = 0; jb < 4096; jb += 128) {
    const int j0 = jb + 2 * lane;
    const float2 vx = *(const float2*)&px[j0];
    const float2 vy = *(const float2*)&py[j0];
    const float2 vz = *(const float2*)&pz[j0];
    const float dx0 = vx.x - qx, dy0 = vy.x - qy, dz0 = vz.x - qz;
    const float dx1 = vx.y - qx, dy1 = vy.y - qy, dz1 = vz.y - qz;
    // match numpy fp32 (no fma contraction, same summation order)
    const float d20 = __fadd_rn(__fadd_rn(__fmul_rn(dx0, dx0), __fmul_rn(dy0, dy0)),
                                __fmul_rn(dz0, dz0));
    const float d21 = __fadd_rn(__fadd_rn(__fmul_rn(dx1, dx1), __fmul_rn(dy1, dy1)),
                                __fmul_rn(dz1, dz1));
    const bool h0 = d20 < R2, h1 = d21 < R2;
    const unsigned long long m0 = __ballot(h0), m1 = __ballot(h1);
    if (m0 | m1) {
      if (cnt == 0) {
        const int c0 = m0 ? 2 * (int)__builtin_ctzll(m0) : 4096;
        const int c1 = m1 ? 2 * (int)__builtin_ctzll(m1) + 1 : 4096;
        first = jb + (c0 < c1 ? c0 : c1);
      }
      const unsigned long long below = (1ull << lane) - 1ull;
      const int pos0 = cnt + (int)__popcll(m0 & below) + (int)__popcll(m1 & below);
      const int pos1 = pos0 + (h0 ? 1 : 0);
      if (h0 && pos0 < 32) row[pos0] = j0;
      if (h1 && pos1 < 32) row[pos1] = j0 + 1;
      cnt += (int)__popcll(m0) + (int)__popcll(m1);
      if (cnt >= 32) break;   // uniform
    }
  }
  for (int s = cnt + lane; s < 32; s += 64) row[s] = first;
}

// ---------------- K2: u, q per point (8 threads/point) ----------------
__global__ __launch_bounds__(256) void k_uq(const float* __restrict__ p,
                                            const float* __restrict__ x,
                                            const float* __restrict__ W1t,
                                            float* __restrict__ u, float* __restrict__ q) {
  const int t = threadIdx.x;
  const int gb = blockIdx.x;                 // 512 blocks
  const int b = gb >> 7;
  const int n = ((gb & 127) << 5) + (t & 31);
  const int os = (t >> 5) << 3;              // 8-output slice
  const int pn = (b << 12) + n;
  float f[35];
  const float* pb = p + pn * 3;
  f[0] = pb[0]; f[1] = pb[1]; f[2] = pb[2];
  const float* xb = x + (b << 17) + n;
#pragma unroll
  for (int c = 0; c < 32; ++c) f[3 + c] = xb[c << 12];
  float acc[8];
#pragma unroll
  for (int o = 0; o < 8; ++o) acc[o] = 0.f;
#pragma unroll
  for (int c = 0; c < 35; ++c) {
    const float fc = f[c];
    const float4* wp = (const float4*)(W1t + (c << 6) + os);
    const float4 w0 = wp[0], w1 = wp[1];
    acc[0] = fmaf(w0.x, fc, acc[0]); acc[1] = fmaf(w0.y, fc, acc[1]);
    acc[2] = fmaf(w0.z, fc, acc[2]); acc[3] = fmaf(w0.w, fc, acc[3]);
    acc[4] = fmaf(w1.x, fc, acc[4]); acc[5] = fmaf(w1.y, fc, acc[5]);
    acc[6] = fmaf(w1.z, fc, acc[6]); acc[7] = fmaf(w1.w, fc, acc[7]);
    if (c == 2) {
      *(float4*)(q + (pn << 6) + os)     = make_float4(acc[0], acc[1], acc[2], acc[3]);
      *(float4*)(q + (pn << 6) + os + 4) = make_float4(acc[4], acc[5], acc[6], acc[7]);
    }
  }
  *(float4*)(u + (pn << 6) + os)     = make_float4(acc[0], acc[1], acc[2], acc[3]);
  *(float4*)(u + (pn << 6) + os + 4) = make_float4(acc[4], acc[5], acc[6], acc[7]);
}

// ---------------- K3: BN1 stats (lane=channel) + block-reduce + atomic ----------------
__global__ __launch_bounds__(256) void k_bn1(const float* __restrict__ u,
                                             const float* __restrict__ q,
                                             const int* __restrict__ idx,
                                             float* __restrict__ part1b) {
  __shared__ float red[8][64];
  const int blkS = ((blockIdx.x & 7) << 6) + (blockIdx.x >> 3);   // XCD swizzle, 512 blocks
  const int w = threadIdx.x >> 6, lane = threadIdx.x & 63;
  const int gw = (blkS << 2) + w;            // 2048 waves
  float s1 = 0.f, s2 = 0.f;
  const int base = gw << 3;                  // 8 points per wave
  for (int t = 0; t < 8; ++t) {
    const int pn = base + t;
    const float qv = q[(pn << 6) + lane];
    const int* irow = idx + (pn << 5);
    int myj = (lane < 32) ? irow[lane] : 0;
    const int bb = (pn >> 12) << 12;
#pragma unroll 8
    for (int k = 0; k < 32; ++k) {
      int jj = __shfl(myj, k);
      float y = u[((bb + jj) << 6) + lane] - qv;
      s1 += y;
      s2 = fmaf(y, y, s2);
    }
  }
  red[w][lane] = s1;
  red[4 + w][lane] = s2;
  __syncthreads();
  const int r = threadIdx.x;
  if (r < 128) {
    const int ch = r & 63, sel = (r >= 64) ? 4 : 0;
    const float v = red[sel][ch] + red[sel + 1][ch] + red[sel + 2][ch] + red[sel + 3][ch];
    atomicAdd(&part1b[(r << 3) + (blockIdx.x & 7)], v);
  }
}

// ---------------- K4: LDS-free MFMA conv2 + k-reduce + BN2 partials ----------------
// 2048 blocks x 256 thr (4 waves), 8 points/block. Wave: 2 points x 2 k-tiles,
// A-frag built directly from u-gather: lane = (sample l&15, ch (l>>4)*8+e).
__global__ __launch_bounds__(256) void k_stage2(const float* __restrict__ u,
                                                const float* __restrict__ q,
                                                const int* __restrict__ idx,
                                                const float* __restrict__ part1b,
                                                const float* __restrict__ g1,
                                                const float* __restrict__ b1,
                                                const uint32_t* __restrict__ w2frag,
                                                float* __restrict__ part2b,
                                                float* __restrict__ ymax,
                                                float* __restrict__ ymin) {
  __shared__ float ac[128];
  __shared__ float red[8][64];
  const int tid = threadIdx.x, w = tid >> 6, l = tid & 63;
  // ---- inline BN1 finalize (redundant per block, 4 KB read)
  if (tid < 64) {
    float s1 = 0.f, s2 = 0.f;
#pragma unroll
    for (int cix = 0; cix < 8; ++cix) {
      s1 += part1b[(tid << 3) + cix];
      s2 += part1b[((64 + tid) << 3) + cix];
    }
    const float mean = s1 * INVM, var = s2 * INVM - mean * mean;
    const float a = g1[tid] * rsqrtf(var + 1e-5f);
    ac[tid] = a; ac[64 + tid] = b1[tid] - mean * a;
  }
  // ---- B-frags (global, L2-hot)
  bf16x8 bfr[8];
#pragma unroll
  for (int f = 0; f < 8; ++f)
    bfr[f] = __builtin_bit_cast(bf16x8, *(const uint4*)&w2frag[(f << 8) + (l << 2)]);
  __syncthreads();
  const int g = l >> 4;
  const int cb0 = g << 3;                    // 8-ch slice base (kt=0); kt=1 adds 32
  f32x4 a1v[2][2];
#pragma unroll
  for (int kt = 0; kt < 2; ++kt) {
    const int cb = (kt << 5) + cb0;
    a1v[kt][0] = *(const f32x4*)&ac[cb];
    a1v[kt][1] = *(const f32x4*)&ac[cb + 4];
  }
  const int blk0 = blockIdx.x;
  const int blk = ((blk0 & 7) << 8) + (blk0 >> 3);   // bijective XCD swizzle
  const int p0 = blk << 3;
  float sm[4] = {0.f, 0.f, 0.f, 0.f}, sq[4] = {0.f, 0.f, 0.f, 0.f};
#pragma unroll 1
  for (int pi = 0; pi < 2; ++pi) {
    const int pn = p0 + (w << 1) + pi;
    const int bb = (pn >> 12) << 12;
    const float4* qp = (const float4*)(q + (pn << 6));
    f32x4 rv[2][2];   // rv = c1 - a1*q  (h = relu(fma(a1, u, rv)))
#pragma unroll
    for (int kt = 0; kt < 2; ++kt) {
      const int cb = (kt << 5) + cb0;
      const float4 q0 = qp[cb >> 2], q1 = qp[(cb >> 2) + 1];
      const f32x4 c0 = *(const f32x4*)&ac[64 + cb];
      const f32x4 c1_ = *(const f32x4*)&ac[64 + cb + 4];
      rv[kt][0][0] = fmaf(-a1v[kt][0][0], q0.x, c0[0]);
      rv[kt][0][1] = fmaf(-a1v[kt][0][1], q0.y, c0[1]);
      rv[kt][0][2] = fmaf(-a1v[kt][0][2], q0.z, c0[2]);
      rv[kt][0][3] = fmaf(-a1v[kt][0][3], q0.w, c0[3]);
      rv[kt][1][0] = fmaf(-a1v[kt][1][0], q1.x, c1_[0]);
      rv[kt][1][1] = fmaf(-a1v[kt][1][1], q1.y, c1_[1]);
      rv[kt][1][2] = fmaf(-a1v[kt][1][2], q1.z, c1_[2]);
      rv[kt][1][3] = fmaf(-a1v[kt][1][3], q1.w, c1_[3]);
    }
    float mx[4], mn[4];
#pragma unroll
    for (int ot = 0; ot < 4; ++ot) { mx[ot] = -3e38f; mn[ot] = 3e38f; }
#pragma unroll
    for (int kt2 = 0; kt2 < 2; ++kt2) {     // two 16-sample (k-half) tiles
      const int j = idx[(pn << 5) + (kt2 << 4) + (l & 15)];
      const float4* up = (const float4*)(u + ((bb + j) << 6));
      bf16x8 afr[2];
#pragma unroll
      for (int kt = 0; kt < 2; ++kt) {
        const int cb = (kt << 5) + cb0;
        const float4 u0 = up[cb >> 2], u1 = up[(cb >> 2) + 1];
        const f32x4 a0 = a1v[kt][0], a1_ = a1v[kt][1];
        const f32x4 r0 = rv[kt][0], r1 = rv[kt][1];
        const float h0 = fmaxf(fmaf(a0[0], u0.x, r0[0]), 0.f);
        const float h1 = fmaxf(fmaf(a0[1], u0.y, r0[1]), 0.f);
        const float h2 = fmaxf(fmaf(a0[2], u0.z, r0[2]), 0.f);
        const float h3 = fmaxf(fmaf(a0[3], u0.w, r0[3]), 0.f);
        const float h4 = fmaxf(fmaf(a1_[0], u1.x, r1[0]), 0.f);
        const float h5 = fmaxf(fmaf(a1_[1], u1.y, r1[1]), 0.f);
        const float h6 = fmaxf(fmaf(a1_[2], u1.z, r1[2]), 0.f);
        const float h7 = fmaxf(fmaf(a1_[3], u1.w, r1[3]), 0.f);
        uint4 pk;
        pk.x = pack_bf16(h0, h1); pk.y = pack_bf16(h2, h3);
        pk.z = pack_bf16(h4, h5); pk.w = pack_bf16(h6, h7);
        afr[kt] = __builtin_bit_cast(bf16x8, pk);
      }
#pragma unroll
      for (int ot = 0; ot < 4; ++ot) {
        f32x4 acc = {0.f, 0.f, 0.f, 0.f};
        acc = __builtin_amdgcn_mfma_f32_16x16x32_bf16(afr[0], bfr[ot], acc, 0, 0, 0);
        acc = __builtin_amdgcn_mfma_f32_16x16x32_bf16(afr[1], bfr[4 + ot], acc, 0, 0, 0);
#pragma unroll
        for (int e = 0; e < 4; ++e) {
          const float v = acc[e];
          mx[ot] = fmaxf(mx[ot], v); mn[ot] = fminf(mn[ot], v);
          sm[ot] += v; sq[ot] = fmaf(v, v, sq[ot]);
        }
      }
    }
#pragma unroll
    for (int ot = 0; ot < 4; ++ot) {
      float a = fmaxf(mx[ot], __shfl_xor(mx[ot], 16)); a = fmaxf(a, __shfl_xor(a, 32));
      float b = fminf(mn[ot], __shfl_xor(mn[ot], 16)); b = fminf(b, __shfl_xor(b, 32));
      const int o = (ot << 4) + (l & 15);
      if (l < 16)      ymax[(pn << 6) + o] = a;
      else if (l < 32) ymin[(pn << 6) + o] = b;
    }
  }
  // ---- BN2 partials: wave reduce -> LDS -> block reduce -> atomic
#pragma unroll
  for (int ot = 0; ot < 4; ++ot) {
    float s = sm[ot]; s += __shfl_xor(s, 16); s += __shfl_xor(s, 32);
    float t2 = sq[ot]; t2 += __shfl_xor(t2, 16); t2 += __shfl_xor(t2, 32);
    if (l < 16) { red[w][(ot << 4) + l] = s; red[4 + w][(ot << 4) + l] = t2; }
  }
  __syncthreads();
  if (tid < 128) {
    const int ch = tid & 63, sel = (tid >= 64) ? 4 : 0;
    const float v = red[sel][ch] + red[sel + 1][ch] + red[sel + 2][ch] + red[sel + 3][ch];
    atomicAdd(&part2b[(tid << 3) + (blk0 & 7)], v);
  }
}

// ---------------- K5: output (inline a2c2 + LDS 64x64 transpose) ----------------
__global__ __launch_bounds__(256) void k_out(const float* __restrict__ ymax,
                                             const float* __restrict__ ymin,
                                             const float* __restrict__ part2b,
                                             const float* __restrict__ g2,
                                             const float* __restrict__ b2,
                                             float* __restrict__ out) {
  __shared__ float ac[128];
  __shared__ float tile[64][65];
  const int tid = threadIdx.x;
  if (tid < 64) {
    float s1 = 0.f, s2 = 0.f;
#pragma unroll
    for (int cix = 0; cix < 8; ++cix) {
      s1 += part2b[(tid << 3) + cix];
      s2 += part2b[((64 + tid) << 3) + cix];
    }
    const float mean = s1 * INVM, var = s2 * INVM - mean * mean;
    const float a = g2[tid] * rsqrtf(var + 1e-5f);
    ac[tid] = a; ac[64 + tid] = b2[tid] - mean * a;
  }
  __syncthreads();
  const int b = blockIdx.x >> 6, nt = blockIdx.x & 63;   // 256 blocks
  const int pnbase = (b << 12) + (nt << 6);
#pragma unroll
  for (int i = 0; i < 16; ++i) {
    const int e = i * 256 + tid;
    const int nl = e >> 6, o = e & 63;
    const float a = ac[o], c = ac[64 + o];
    const int src = ((pnbase + nl) << 6) + o;
    const float v = (a >= 0.f) ? ymax[src] : ymin[src];
    tile[nl][o] = fmaxf(fmaf(a, v, c), 0.f);
  }
  __syncthreads();
#pragma unroll
  for (int i = 0; i < 16; ++i) {
    const int e = i * 256 + tid;
    const int ol = e >> 6, nl = e & 63;
    out[(b << 18) + (ol << 12) + (nt << 6) + nl] = tile[nl][ol];
  }
}

extern "C" void kernel_launch(void* const* d_in, const int* in_sizes, int n_in,
                              void* d_out, int out_size, void* d_ws, size_t ws_size,
                              hipStream_t stream) {
  const float* p  = (const float*)d_in[0];
  const float* x  = (const float*)d_in[1];
  const float* W1 = (const float*)d_in[2];
  const float* g1 = (const float*)d_in[3];
  const float* b1 = (const float*)d_in[4];
  const float* W2 = (const float*)d_in[5];
  const float* g2 = (const float*)d_in[6];
  const float* b2 = (const float*)d_in[7];
  float* out = (float*)d_out;

  char* ws = (char*)d_ws;
  size_t off = 0;
  int* idx        = (int*)(ws + off);      off += 2097152;   // B*N*32 int
  float* u        = (float*)(ws + off);    off += 4194304;   // B*N*64 f32
  float* q        = (float*)(ws + off);    off += 4194304;
  float* W1t      = (float*)(ws + off);    off += 16384;
  uint32_t* w2f   = (uint32_t*)(ws + off); off += 8192;      // 8 frags * 64 lanes * 16B
  float* part1b   = (float*)(ws + off);    off += 4096;      // [128][8]
  float* part2b   = (float*)(ws + off);    off += 4096;      // [128][8]
  float* ymax     = (float*)(ws + off);    off += 4194304;   // [pn][o]
  float* ymin     = (float*)(ws + off);    off += 4194304;   // ~18.9 MB total

  k_bq_prep<<<dim3(1025), dim3(1024), 0, stream>>>(p, idx, W1, W2, W1t, w2f, part1b, part2b);
  k_uq<<<dim3(512), dim3(256), 0, stream>>>(p, x, W1t, u, q);
  k_bn1<<<dim3(512), dim3(256), 0, stream>>>(u, q, idx, part1b);
  k_stage2<<<dim3(2048), dim3(256), 0, stream>>>(u, q, idx, part1b, g1, b1, w2f,
                                                 part2b, ymax, ymin);
  k_out<<<dim3(256), dim3(256), 0, stream>>>(ymax, ymin, part2b, g2, b2, out);
}

// Round 5
// 77.315 us; speedup vs baseline: 1.6295x; 1.6295x over previous
//
#include <hip/hip_runtime.h>
#include <stdint.h>

// LocalAggregation (PointNet++ SA layer, B=4 N=4096 C=32 K=32, 35->64->64)
//
// 5-kernel pipeline:
//  K1 bq_prep : blocks [0,1024): ball query -> idx[b][n][32]
//               block 1024: W1t transpose, W2 MFMA-frag pack, zero part1b/part2b
//  K2 uq      : u = W1[:,3:]x + W1[:,:3]p ; q = W1[:,:3]p   (y1 = u[j]-q[n])
//  K3 bn1     : per-channel sum/sumsq of y1; block-reduce -> atomicAdd part1b[xcd][128]
//  K4 stage2  : inline BN1 finalize; coalesced row-gather (4 lanes/row) -> h ->
//               swizzled LDS tile -> MFMA conv2; per-(n,o) max/min over k;
//               BN2 partials -> atomicAdd part2b[xcd][128]. XCD-swizzled blocks.
//  K5 out     : inline BN2 finalize; 64x64 LDS transpose, coalesced.

#define R2 0.01f
#define INVM (1.0f / 524288.0f)

typedef __bf16 bf16x8 __attribute__((ext_vector_type(8)));
typedef float f32x4 __attribute__((ext_vector_type(4)));

__device__ __forceinline__ uint32_t pack_bf16(float a, float b) {
  uint32_t ua = __float_as_uint(a), ub = __float_as_uint(b);
  ua += 0x7fffu + ((ua >> 16) & 1u);
  ub += 0x7fffu + ((ub >> 16) & 1u);
  return (ua >> 16) | (ub & 0xffff0000u);
}

// ---------------- K1: ball query + prep ----------------
__global__ __launch_bounds__(1024) void k_bq_prep(const float* __restrict__ p,
                                                  int* __restrict__ idx,
                                                  const float* __restrict__ W1,
                                                  const float* __restrict__ W2,
                                                  float* __restrict__ W1t,
                                                  uint32_t* __restrict__ w2frag,
                                                  float* __restrict__ part1b,
                                                  float* __restrict__ part2b) {
  __shared__ float px[4096], py[4096], pz[4096];
  if (blockIdx.x >= 1024) {   // prep block
    const int t = threadIdx.x;
    for (int tt = t; tt < 2240; tt += 1024) {
      const int o = tt / 35, c = tt - o * 35;
      W1t[(c << 6) + o] = W1[tt];
    }
    for (int tt = t; tt < 2048; tt += 1024) {
      const int e2 = tt & 3, lane = (tt >> 2) & 63, frag = tt >> 8;
      const int kt = frag >> 2, ot = frag & 3;
      const int c0 = kt * 32 + ((lane >> 4) << 3) + e2 * 2;
      const int o = ot * 16 + (lane & 15);
      w2frag[tt] = pack_bf16(W2[(o << 6) + c0], W2[(o << 6) + c0 + 1]);
    }
    part1b[t] = 0.f;   // [8][128] = 1024 floats each
    part2b[t] = 0.f;
    return;
  }
  const int b = blockIdx.x >> 8;             // 256 blocks per batch
  const int nb = (blockIdx.x & 255) << 4;    // 16 queries per block (1 per wave)
  const float* pb = p + b * 12288;
  for (int i = threadIdx.x; i < 4096; i += 1024) {
    px[i] = pb[3 * i]; py[i] = pb[3 * i + 1]; pz[i] = pb[3 * i + 2];
  }
  __syncthreads();
  const int wv = threadIdx.x >> 6, lane = threadIdx.x & 63;
  const int n = nb + wv;
  const float qx = px[n], qy = py[n], qz = pz[n];
  int* row = idx + (((b << 12) + n) << 5);
  int cnt = 0, first = 0;
  for (int jb = 0; jb < 4096; jb += 128) {
    const int j0 = jb + 2 * lane;
    const float2 vx = *(const float2*)&px[j0];
    const float2 vy = *(const float2*)&py[j0];
    const float2 vz = *(const float2*)&pz[j0];
    const float dx0 = vx.x - qx, dy0 = vy.x - qy, dz0 = vz.x - qz;
    const float dx1 = vx.y - qx, dy1 = vy.y - qy, dz1 = vz.y - qz;
    // match numpy fp32 (no fma contraction, same summation order)
    const float d20 = __fadd_rn(__fadd_rn(__fmul_rn(dx0, dx0), __fmul_rn(dy0, dy0)),
                                __fmul_rn(dz0, dz0));
    const float d21 = __fadd_rn(__fadd_rn(__fmul_rn(dx1, dx1), __fmul_rn(dy1, dy1)),
                                __fmul_rn(dz1, dz1));
    const bool h0 = d20 < R2, h1 = d21 < R2;
    const unsigned long long m0 = __ballot(h0), m1 = __ballot(h1);
    if (m0 | m1) {
      if (cnt == 0) {
        const int c0 = m0 ? 2 * (int)__builtin_ctzll(m0) : 4096;
        const int c1 = m1 ? 2 * (int)__builtin_ctzll(m1) + 1 : 4096;
        first = jb + (c0 < c1 ? c0 : c1);
      }
      const unsigned long long below = (1ull << lane) - 1ull;
      const int pos0 = cnt + (int)__popcll(m0 & below) + (int)__popcll(m1 & below);
      const int pos1 = pos0 + (h0 ? 1 : 0);
      if (h0 && pos0 < 32) row[pos0] = j0;
      if (h1 && pos1 < 32) row[pos1] = j0 + 1;
      cnt += (int)__popcll(m0) + (int)__popcll(m1);
      if (cnt >= 32) break;   // uniform
    }
  }
  for (int s = cnt + lane; s < 32; s += 64) row[s] = first;
}

// ---------------- K2: u, q per point (8 threads/point) ----------------
__global__ __launch_bounds__(256) void k_uq(const float* __restrict__ p,
                                            const float* __restrict__ x,
                                            const float* __restrict__ W1t,
                                            float* __restrict__ u, float* __restrict__ q) {
  const int t = threadIdx.x;
  const int gb = blockIdx.x;                 // 512 blocks
  const int b = gb >> 7;
  const int n = ((gb & 127) << 5) + (t & 31);
  const int os = (t >> 5) << 3;              // 8-output slice
  const int pn = (b << 12) + n;
  float f[35];
  const float* pb = p + pn * 3;
  f[0] = pb[0]; f[1] = pb[1]; f[2] = pb[2];
  const float* xb = x + (b << 17) + n;
#pragma unroll
  for (int c = 0; c < 32; ++c) f[3 + c] = xb[c << 12];
  float acc[8];
#pragma unroll
  for (int o = 0; o < 8; ++o) acc[o] = 0.f;
#pragma unroll
  for (int c = 0; c < 35; ++c) {
    const float fc = f[c];
    const float4* wp = (const float4*)(W1t + (c << 6) + os);
    const float4 w0 = wp[0], w1 = wp[1];
    acc[0] = fmaf(w0.x, fc, acc[0]); acc[1] = fmaf(w0.y, fc, acc[1]);
    acc[2] = fmaf(w0.z, fc, acc[2]); acc[3] = fmaf(w0.w, fc, acc[3]);
    acc[4] = fmaf(w1.x, fc, acc[4]); acc[5] = fmaf(w1.y, fc, acc[5]);
    acc[6] = fmaf(w1.z, fc, acc[6]); acc[7] = fmaf(w1.w, fc, acc[7]);
    if (c == 2) {
      *(float4*)(q + (pn << 6) + os)     = make_float4(acc[0], acc[1], acc[2], acc[3]);
      *(float4*)(q + (pn << 6) + os + 4) = make_float4(acc[4], acc[5], acc[6], acc[7]);
    }
  }
  *(float4*)(u + (pn << 6) + os)     = make_float4(acc[0], acc[1], acc[2], acc[3]);
  *(float4*)(u + (pn << 6) + os + 4) = make_float4(acc[4], acc[5], acc[6], acc[7]);
}

// ---------------- K3: BN1 stats (lane=channel) + block-reduce + atomic ----------------
__global__ __launch_bounds__(256) void k_bn1(const float* __restrict__ u,
                                             const float* __restrict__ q,
                                             const int* __restrict__ idx,
                                             float* __restrict__ part1b) {
  __shared__ float red[8][64];
  const int blkS = ((blockIdx.x & 7) << 6) + (blockIdx.x >> 3);   // XCD swizzle, 512 blocks
  const int w = threadIdx.x >> 6, lane = threadIdx.x & 63;
  const int gw = (blkS << 2) + w;            // 2048 waves
  float s1 = 0.f, s2 = 0.f;
  const int base = gw << 3;                  // 8 points per wave
  for (int t = 0; t < 8; ++t) {
    const int pn = base + t;
    const float qv = q[(pn << 6) + lane];
    const int* irow = idx + (pn << 5);
    int myj = (lane < 32) ? irow[lane] : 0;
    const int bb = (pn >> 12) << 12;
#pragma unroll 8
    for (int k = 0; k < 32; ++k) {
      int jj = __shfl(myj, k);
      float y = u[((bb + jj) << 6) + lane] - qv;
      s1 += y;
      s2 = fmaf(y, y, s2);
    }
  }
  red[w][lane] = s1;
  red[4 + w][lane] = s2;
  __syncthreads();
  const int r = threadIdx.x;
  if (r < 128) {
    const int ch = r & 63, sel = (r >= 64) ? 4 : 0;
    const float v = red[sel][ch] + red[sel + 1][ch] + red[sel + 2][ch] + red[sel + 3][ch];
    atomicAdd(&part1b[((blockIdx.x & 7) << 7) + r], v);   // XCD-private lines
  }
}

// ---------------- K4: coalesced-gather MFMA conv2 + k-reduce + BN2 partials ----------------
// 2048 blocks x 256 thr (4 waves), 8 points (256 samples) per block.
// Gather: 4 consecutive lanes own one u-row (contiguous 64B per lane-quad per inst).
// LDS h-tile: byte = s*128 + ch*2, swizzle ^= (s&7)<<4 (round-2-proven layout).
__global__ __launch_bounds__(256) void k_stage2(const float* __restrict__ u,
                                                const int* __restrict__ idx,
                                                const float* __restrict__ q,
                                                const float* __restrict__ part1b,
                                                const float* __restrict__ g1,
                                                const float* __restrict__ b1,
                                                const uint32_t* __restrict__ w2frag,
                                                float* __restrict__ part2b,
                                                float* __restrict__ ymax,
                                                float* __restrict__ ymin) {
  __shared__ uint32_t hl[8192];   // 32 KB h tile: 256 samples x 128 B
  __shared__ float rs[8][64];     // rs = c1 - a1*q per (point, ch)
  __shared__ int   idxs[256];
  __shared__ float ac[128];
  __shared__ float red[8][64];
  const int tid = threadIdx.x, w = tid >> 6, l = tid & 63;
  const int blk0 = blockIdx.x;
  const int blk = ((blk0 & 7) << 8) + (blk0 >> 3);   // bijective XCD swizzle
  const int p0 = blk << 3;
  const int bb = (p0 >> 12) << 12;                   // block is within one batch

  // idx block preload (coalesced, kills idx->u dependency)
  idxs[tid] = idx[(p0 << 5) + tid];
  // q block into regs (coalesced)
  const float qa = q[(p0 << 6) + tid];
  const float qb = q[(p0 << 6) + 256 + tid];
  // inline BN1 finalize
  if (tid < 64) {
    float s1 = 0.f, s2 = 0.f;
#pragma unroll
    for (int xx = 0; xx < 8; ++xx) {
      s1 += part1b[(xx << 7) + tid];
      s2 += part1b[(xx << 7) + 64 + tid];
    }
    const float mean = s1 * INVM, var = s2 * INVM - mean * mean;
    const float a = g1[tid] * rsqrtf(var + 1e-5f);
    ac[tid] = a; ac[64 + tid] = b1[tid] - mean * a;
  }
  __syncthreads();
  rs[tid >> 6][tid & 63] = fmaf(-ac[tid & 63], qa, ac[64 + (tid & 63)]);
  rs[4 + (tid >> 6)][tid & 63] = fmaf(-ac[tid & 63], qb, ac[64 + (tid & 63)]);
  __syncthreads();

  // ---- phase 1: gather rows coalesced, compute h, store swizzled LDS bf16
  const int c = tid & 3;                 // 64-B chunk owner within row
#pragma unroll
  for (int pass = 0; pass < 4; ++pass) {
    const int r = (pass << 6) + (tid >> 2);   // sample row 0..255
    const int pt = r >> 5;
    const int j = idxs[r];
    const float* up = u + ((bb + j) << 6);
    float4 uv[4];
#pragma unroll
    for (int i = 0; i < 4; ++i) uv[i] = *(const float4*)(up + (i << 4) + (c << 2));
#pragma unroll
    for (int i = 0; i < 4; ++i) {
      const int ch0 = (i << 4) + (c << 2);
      const f32x4 a = *(const f32x4*)&ac[ch0];
      const f32x4 rv = *(const f32x4*)&rs[pt][ch0];
      const float h0 = fmaxf(fmaf(a[0], uv[i].x, rv[0]), 0.f);
      const float h1 = fmaxf(fmaf(a[1], uv[i].y, rv[1]), 0.f);
      const float h2 = fmaxf(fmaf(a[2], uv[i].z, rv[2]), 0.f);
      const float h3 = fmaxf(fmaf(a[3], uv[i].w, rv[3]), 0.f);
      int byte = (r << 7) + (ch0 << 1);
      byte ^= (r & 7) << 4;
      *(uint2*)((char*)hl + byte) = make_uint2(pack_bf16(h0, h1), pack_bf16(h2, h3));
    }
  }

  // ---- B-frags (global, L2-hot)
  bf16x8 bfr[8];
#pragma unroll
  for (int f = 0; f < 8; ++f)
    bfr[f] = __builtin_bit_cast(bf16x8, *(const uint4*)&w2frag[(f << 8) + (l << 2)]);
  __syncthreads();

  // ---- phase 2: per point: 16 MFMAs, stats
  float sm[4] = {0.f, 0.f, 0.f, 0.f}, sq[4] = {0.f, 0.f, 0.f, 0.f};
#pragma unroll 1
  for (int pi = 0; pi < 2; ++pi) {
    const int ptl = (w << 1) + pi;
    const int pn = p0 + ptl;
    float mx[4], mn[4];
#pragma unroll
    for (int ot = 0; ot < 4; ++ot) { mx[ot] = -3e38f; mn[ot] = 3e38f; }
#pragma unroll
    for (int kt2 = 0; kt2 < 2; ++kt2) {     // two 16-sample tiles
      bf16x8 afr[2];
#pragma unroll
      for (int kt = 0; kt < 2; ++kt) {
        const int srow = (ptl << 5) + (kt2 << 4) + (l & 15);
        int byte = (srow << 7) + (kt << 6) + ((l >> 4) << 4);
        byte ^= (srow & 7) << 4;
        afr[kt] = *(const bf16x8*)((const char*)hl + byte);
      }
#pragma unroll
      for (int ot = 0; ot < 4; ++ot) {
        f32x4 acc = {0.f, 0.f, 0.f, 0.f};
        acc = __builtin_amdgcn_mfma_f32_16x16x32_bf16(afr[0], bfr[ot], acc, 0, 0, 0);
        acc = __builtin_amdgcn_mfma_f32_16x16x32_bf16(afr[1], bfr[4 + ot], acc, 0, 0, 0);
#pragma unroll
        for (int e = 0; e < 4; ++e) {
          const float v = acc[e];
          mx[ot] = fmaxf(mx[ot], v); mn[ot] = fminf(mn[ot], v);
          sm[ot] += v; sq[ot] = fmaf(v, v, sq[ot]);
        }
      }
    }
#pragma unroll
    for (int ot = 0; ot < 4; ++ot) {
      float a = fmaxf(mx[ot], __shfl_xor(mx[ot], 16)); a = fmaxf(a, __shfl_xor(a, 32));
      float b = fminf(mn[ot], __shfl_xor(mn[ot], 16)); b = fminf(b, __shfl_xor(b, 32));
      const int o = (ot << 4) + (l & 15);
      if (l < 16)      ymax[(pn << 6) + o] = a;
      else if (l < 32) ymin[(pn << 6) + o] = b;
    }
  }
  // ---- BN2 partials: wave reduce -> LDS -> block reduce -> atomic (XCD-private)
#pragma unroll
  for (int ot = 0; ot < 4; ++ot) {
    float s = sm[ot]; s += __shfl_xor(s, 16); s += __shfl_xor(s, 32);
    float t2 = sq[ot]; t2 += __shfl_xor(t2, 16); t2 += __shfl_xor(t2, 32);
    if (l < 16) { red[w][(ot << 4) + l] = s; red[4 + w][(ot << 4) + l] = t2; }
  }
  __syncthreads();
  if (tid < 128) {
    const int ch = tid & 63, sel = (tid >= 64) ? 4 : 0;
    const float v = red[sel][ch] + red[sel + 1][ch] + red[sel + 2][ch] + red[sel + 3][ch];
    atomicAdd(&part2b[((blk0 & 7) << 7) + tid], v);
  }
}

// ---------------- K5: output (inline a2c2 + LDS 64x64 transpose) ----------------
__global__ __launch_bounds__(256) void k_out(const float* __restrict__ ymax,
                                             const float* __restrict__ ymin,
                                             const float* __restrict__ part2b,
                                             const float* __restrict__ g2,
                                             const float* __restrict__ b2,
                                             float* __restrict__ out) {
  __shared__ float ac[128];
  __shared__ float tile[64][65];
  const int tid = threadIdx.x;
  if (tid < 64) {
    float s1 = 0.f, s2 = 0.f;
#pragma unroll
    for (int xx = 0; xx < 8; ++xx) {
      s1 += part2b[(xx << 7) + tid];
      s2 += part2b[(xx << 7) + 64 + tid];
    }
    const float mean = s1 * INVM, var = s2 * INVM - mean * mean;
    const float a = g2[tid] * rsqrtf(var + 1e-5f);
    ac[tid] = a; ac[64 + tid] = b2[tid] - mean * a;
  }
  __syncthreads();
  const int b = blockIdx.x >> 6, nt = blockIdx.x & 63;   // 256 blocks
  const int pnbase = (b << 12) + (nt << 6);
#pragma unroll
  for (int i = 0; i < 16; ++i) {
    const int e = i * 256 + tid;
    const int nl = e >> 6, o = e & 63;
    const float a = ac[o], c = ac[64 + o];
    const int src = ((pnbase + nl) << 6) + o;
    const float v = (a >= 0.f) ? ymax[src] : ymin[src];
    tile[nl][o] = fmaxf(fmaf(a, v, c), 0.f);
  }
  __syncthreads();
#pragma unroll
  for (int i = 0; i < 16; ++i) {
    const int e = i * 256 + tid;
    const int ol = e >> 6, nl = e & 63;
    out[(b << 18) + (ol << 12) + (nt << 6) + nl] = tile[nl][ol];
  }
}

extern "C" void kernel_launch(void* const* d_in, const int* in_sizes, int n_in,
                              void* d_out, int out_size, void* d_ws, size_t ws_size,
                              hipStream_t stream) {
  const float* p  = (const float*)d_in[0];
  const float* x  = (const float*)d_in[1];
  const float* W1 = (const float*)d_in[2];
  const float* g1 = (const float*)d_in[3];
  const float* b1 = (const float*)d_in[4];
  const float* W2 = (const float*)d_in[5];
  const float* g2 = (const float*)d_in[6];
  const float* b2 = (const float*)d_in[7];
  float* out = (float*)d_out;

  char* ws = (char*)d_ws;
  size_t off = 0;
  int* idx        = (int*)(ws + off);      off += 2097152;   // B*N*32 int
  float* u        = (float*)(ws + off);    off += 4194304;   // B*N*64 f32
  float* q        = (float*)(ws + off);    off += 4194304;
  float* W1t      = (float*)(ws + off);    off += 16384;
  uint32_t* w2f   = (uint32_t*)(ws + off); off += 8192;      // 8 frags * 64 lanes * 16B
  float* part1b   = (float*)(ws + off);    off += 4096;      // [8][128] XCD-private
  float* part2b   = (float*)(ws + off);    off += 4096;      // [8][128]
  float* ymax     = (float*)(ws + off);    off += 4194304;   // [pn][o]
  float* ymin     = (float*)(ws + off);    off += 4194304;   // ~18.9 MB total

  k_bq_prep<<<dim3(1025), dim3(1024), 0, stream>>>(p, idx, W1, W2, W1t, w2f, part1b, part2b);
  k_uq<<<dim3(512), dim3(256), 0, stream>>>(p, x, W1t, u, q);
  k_bn1<<<dim3(512), dim3(256), 0, stream>>>(u, q, idx, part1b);
  k_stage2<<<dim3(2048), dim3(256), 0, stream>>>(u, idx, q, part1b, g1, b1, w2f,
                                                 part2b, ymax, ymin);
  k_out<<<dim3(256), dim3(256), 0, stream>>>(ymax, ymin, part2b, g2, b2, out);
}

// Round 6
// 77.166 us; speedup vs baseline: 1.6326x; 1.0019x over previous
//
#include <hip/hip_runtime.h>
#include <stdint.h>

// LocalAggregation (PointNet++ SA layer, B=4 N=4096 C=32 K=32, 35->64->64)
//
// 4-kernel pipeline:
//  K1 fused1 : blocks [0,128): uq (u = W1[:,3:]x + W1[:,:3]p ; q = W1[:,:3]p, W1 via LDS)
//              block 128: W2 MFMA-frag pack, zero part1b/part2b
//              blocks [129,1153): ball query -> idx[b][n][32]
//  K2 bn1    : coalesced gather (idx/q staged in LDS, 4 lanes/row) -> per-channel
//              sum/sumsq -> shuffle+LDS reduce -> atomicAdd part1b[xcd][128]
//  K3 stage2 : inline BN1 finalize; coalesced row-gather -> h -> swizzled LDS tile ->
//              MFMA conv2; per-(n,o) max/min over k; BN2 partials -> part2b[xcd][128]
//  K4 out    : inline BN2 finalize; 64x64 LDS transpose, coalesced.

#define R2 0.01f
#define INVM (1.0f / 524288.0f)

typedef __bf16 bf16x8 __attribute__((ext_vector_type(8)));
typedef float f32x4 __attribute__((ext_vector_type(4)));

__device__ __forceinline__ uint32_t pack_bf16(float a, float b) {
  uint32_t ua = __float_as_uint(a), ub = __float_as_uint(b);
  ua += 0x7fffu + ((ua >> 16) & 1u);
  ub += 0x7fffu + ((ub >> 16) & 1u);
  return (ua >> 16) | (ub & 0xffff0000u);
}

// ---------------- K1: fused uq + prep + ball query ----------------
__global__ __launch_bounds__(1024) void k_fused1(const float* __restrict__ p,
                                                 const float* __restrict__ x,
                                                 const float* __restrict__ W1,
                                                 const float* __restrict__ W2,
                                                 int* __restrict__ idx,
                                                 float* __restrict__ u,
                                                 float* __restrict__ q,
                                                 uint32_t* __restrict__ w2frag,
                                                 float* __restrict__ part1b,
                                                 float* __restrict__ part2b) {
  __shared__ __align__(16) float sm[12288];   // 48 KB
  const int bid = blockIdx.x;
  const int tid = threadIdx.x;

  if (bid < 128) {
    // ---- uq: 128 points/block, 8 threads/point ----
    float* W1s = sm;   // transposed [c][64]
    for (int tt = tid; tt < 2240; tt += 1024) {
      const int o = tt / 35, cc = tt - o * 35;
      W1s[(cc << 6) + o] = W1[tt];
    }
    __syncthreads();
    const int t = tid & 255, sb = tid >> 8;
    const int g = (bid << 7) + (sb << 5) + (t & 31);   // global point id
    const int b = g >> 12, nl = g & 4095;
    const int os = (t >> 5) << 3;                      // 8-output slice
    float f[35];
    const float* pb = p + g * 3;
    f[0] = pb[0]; f[1] = pb[1]; f[2] = pb[2];
    const float* xb = x + (b << 17) + nl;
#pragma unroll
    for (int cc = 0; cc < 32; ++cc) f[3 + cc] = xb[cc << 12];
    float acc[8];
#pragma unroll
    for (int o = 0; o < 8; ++o) acc[o] = 0.f;
#pragma unroll
    for (int cc = 0; cc < 35; ++cc) {
      const float fc = f[cc];
      const float4* wp = (const float4*)(W1s + (cc << 6) + os);
      const float4 w0 = wp[0], w1 = wp[1];
      acc[0] = fmaf(w0.x, fc, acc[0]); acc[1] = fmaf(w0.y, fc, acc[1]);
      acc[2] = fmaf(w0.z, fc, acc[2]); acc[3] = fmaf(w0.w, fc, acc[3]);
      acc[4] = fmaf(w1.x, fc, acc[4]); acc[5] = fmaf(w1.y, fc, acc[5]);
      acc[6] = fmaf(w1.z, fc, acc[6]); acc[7] = fmaf(w1.w, fc, acc[7]);
      if (cc == 2) {
        *(float4*)(q + (g << 6) + os)     = make_float4(acc[0], acc[1], acc[2], acc[3]);
        *(float4*)(q + (g << 6) + os + 4) = make_float4(acc[4], acc[5], acc[6], acc[7]);
      }
    }
    *(float4*)(u + (g << 6) + os)     = make_float4(acc[0], acc[1], acc[2], acc[3]);
    *(float4*)(u + (g << 6) + os + 4) = make_float4(acc[4], acc[5], acc[6], acc[7]);
    return;
  }

  if (bid == 128) {
    // ---- prep: w2frag pack + zero atomic accumulators ----
    for (int tt = tid; tt < 2048; tt += 1024) {
      const int e2 = tt & 3, lane = (tt >> 2) & 63, frag = tt >> 8;
      const int kt = frag >> 2, ot = frag & 3;
      const int c0 = kt * 32 + ((lane >> 4) << 3) + e2 * 2;
      const int o = ot * 16 + (lane & 15);
      w2frag[tt] = pack_bf16(W2[(o << 6) + c0], W2[(o << 6) + c0 + 1]);
    }
    part1b[tid] = 0.f;   // [8][128] = 1024 floats each
    part2b[tid] = 0.f;
    return;
  }

  // ---- ball query ----
  float* px = sm;
  float* py = sm + 4096;
  float* pz = sm + 8192;
  const int bid2 = bid - 129;
  const int b = bid2 >> 8;                   // 256 blocks per batch
  const int nb = (bid2 & 255) << 4;          // 16 queries per block (1 per wave)
  const float* pb = p + b * 12288;
  for (int i = tid; i < 4096; i += 1024) {
    px[i] = pb[3 * i]; py[i] = pb[3 * i + 1]; pz[i] = pb[3 * i + 2];
  }
  __syncthreads();
  const int wv = tid >> 6, lane = tid & 63;
  const int n = nb + wv;
  const float qx = px[n], qy = py[n], qz = pz[n];
  int* row = idx + (((b << 12) + n) << 5);
  int cnt = 0, first = 0;
  for (int jb = 0; jb < 4096; jb += 128) {
    const int j0 = jb + 2 * lane;
    const float2 vx = *(const float2*)&px[j0];
    const float2 vy = *(const float2*)&py[j0];
    const float2 vz = *(const float2*)&pz[j0];
    const float dx0 = vx.x - qx, dy0 = vy.x - qy, dz0 = vz.x - qz;
    const float dx1 = vx.y - qx, dy1 = vy.y - qy, dz1 = vz.y - qz;
    // match numpy fp32 (no fma contraction, same summation order)
    const float d20 = __fadd_rn(__fadd_rn(__fmul_rn(dx0, dx0), __fmul_rn(dy0, dy0)),
                                __fmul_rn(dz0, dz0));
    const float d21 = __fadd_rn(__fadd_rn(__fmul_rn(dx1, dx1), __fmul_rn(dy1, dy1)),
                                __fmul_rn(dz1, dz1));
    const bool h0 = d20 < R2, h1 = d21 < R2;
    const unsigned long long m0 = __ballot(h0), m1 = __ballot(h1);
    if (m0 | m1) {
      if (cnt == 0) {
        const int c0 = m0 ? 2 * (int)__builtin_ctzll(m0) : 4096;
        const int c1 = m1 ? 2 * (int)__builtin_ctzll(m1) + 1 : 4096;
        first = jb + (c0 < c1 ? c0 : c1);
      }
      const unsigned long long below = (1ull << lane) - 1ull;
      const int pos0 = cnt + (int)__popcll(m0 & below) + (int)__popcll(m1 & below);
      const int pos1 = pos0 + (h0 ? 1 : 0);
      if (h0 && pos0 < 32) row[pos0] = j0;
      if (h1 && pos1 < 32) row[pos1] = j0 + 1;
      cnt += (int)__popcll(m0) + (int)__popcll(m1);
      if (cnt >= 32) break;   // uniform
    }
  }
  for (int s = cnt + lane; s < 32; s += 64) row[s] = first;
}

// ---------------- K2: BN1 stats, coalesced gather (4 lanes/row) ----------------
// 1024 blocks x 256 thr, 16 points (512 samples) per block. XCD-swizzled.
__global__ __launch_bounds__(256) void k_bn1(const float* __restrict__ u,
                                             const float* __restrict__ q,
                                             const int* __restrict__ idx,
                                             float* __restrict__ part1b) {
  __shared__ int idxs[512];
  __shared__ __align__(16) float qs[1024];   // 16 pts x 64 ch
  __shared__ float red[8][64];               // [w*2+stat][ch]
  const int tid = threadIdx.x;
  const int blk0 = blockIdx.x;
  const int blkS = ((blk0 & 7) << 7) + (blk0 >> 3);   // bijective XCD swizzle
  const int p0 = blkS << 4;
  const int bb = (p0 >> 12) << 12;
  idxs[tid] = idx[(p0 << 5) + tid];
  idxs[256 + tid] = idx[(p0 << 5) + 256 + tid];
#pragma unroll
  for (int i = 0; i < 4; ++i) qs[(i << 8) + tid] = q[(p0 << 6) + (i << 8) + tid];
  __syncthreads();
  const int c = tid & 3;
  float s1[16], s2[16];
#pragma unroll
  for (int i = 0; i < 16; ++i) { s1[i] = 0.f; s2[i] = 0.f; }
#pragma unroll 2
  for (int pass = 0; pass < 8; ++pass) {
    const int r = (pass << 6) + (tid >> 2);   // sample row 0..511
    const int j = idxs[r];
    const int pt = r >> 5;
    const float* up = u + ((bb + j) << 6) + (c << 2);
    const float* qp = qs + (pt << 6) + (c << 2);
#pragma unroll
    for (int i = 0; i < 4; ++i) {
      const float4 uv = *(const float4*)(up + (i << 4));
      const float4 qv = *(const float4*)(qp + (i << 4));
      const float y0 = uv.x - qv.x, y1 = uv.y - qv.y;
      const float y2 = uv.z - qv.z, y3 = uv.w - qv.w;
      s1[4 * i + 0] += y0; s2[4 * i + 0] = fmaf(y0, y0, s2[4 * i + 0]);
      s1[4 * i + 1] += y1; s2[4 * i + 1] = fmaf(y1, y1, s2[4 * i + 1]);
      s1[4 * i + 2] += y2; s2[4 * i + 2] = fmaf(y2, y2, s2[4 * i + 2]);
      s1[4 * i + 3] += y3; s2[4 * i + 3] = fmaf(y3, y3, s2[4 * i + 3]);
    }
  }
  // reduce across the 16 lanes sharing this c (xor 4,8,16,32)
#pragma unroll
  for (int i = 0; i < 16; ++i) {
#pragma unroll
    for (int d = 4; d <= 32; d <<= 1) {
      s1[i] += __shfl_xor(s1[i], d);
      s2[i] += __shfl_xor(s2[i], d);
    }
  }
  const int w = tid >> 6, l = tid & 63;
  if (l < 4) {
#pragma unroll
    for (int i = 0; i < 16; ++i) {
      const int ch = ((i >> 2) << 4) + (l << 2) + (i & 3);
      red[(w << 1)][ch] = s1[i];
      red[(w << 1) + 1][ch] = s2[i];
    }
  }
  __syncthreads();
  if (tid < 128) {
    const int ch = tid & 63, stat = tid >> 6;
    const float v = red[stat][ch] + red[2 + stat][ch] + red[4 + stat][ch] + red[6 + stat][ch];
    atomicAdd(&part1b[((blk0 & 7) << 7) + (stat << 6) + ch], v);   // XCD-private lines
  }
}

// ---------------- K3: coalesced-gather MFMA conv2 + k-reduce + BN2 partials ----------------
__global__ __launch_bounds__(256) void k_stage2(const float* __restrict__ u,
                                                const int* __restrict__ idx,
                                                const float* __restrict__ q,
                                                const float* __restrict__ part1b,
                                                const float* __restrict__ g1,
                                                const float* __restrict__ b1,
                                                const uint32_t* __restrict__ w2frag,
                                                float* __restrict__ part2b,
                                                float* __restrict__ ymax,
                                                float* __restrict__ ymin) {
  __shared__ uint32_t hl[8192];   // 32 KB h tile: 256 samples x 128 B
  __shared__ float rs[8][64];     // rs = c1 - a1*q per (point, ch)
  __shared__ int   idxs[256];
  __shared__ float ac[128];
  __shared__ float red[8][64];
  const int tid = threadIdx.x, w = tid >> 6, l = tid & 63;
  const int blk0 = blockIdx.x;
  const int blk = ((blk0 & 7) << 8) + (blk0 >> 3);   // bijective XCD swizzle
  const int p0 = blk << 3;
  const int bb = (p0 >> 12) << 12;

  idxs[tid] = idx[(p0 << 5) + tid];
  const float qa = q[(p0 << 6) + tid];
  const float qb = q[(p0 << 6) + 256 + tid];
  if (tid < 64) {
    float s1 = 0.f, s2 = 0.f;
#pragma unroll
    for (int xx = 0; xx < 8; ++xx) {
      s1 += part1b[(xx << 7) + tid];
      s2 += part1b[(xx << 7) + 64 + tid];
    }
    const float mean = s1 * INVM, var = s2 * INVM - mean * mean;
    const float a = g1[tid] * rsqrtf(var + 1e-5f);
    ac[tid] = a; ac[64 + tid] = b1[tid] - mean * a;
  }
  __syncthreads();
  rs[tid >> 6][tid & 63] = fmaf(-ac[tid & 63], qa, ac[64 + (tid & 63)]);
  rs[4 + (tid >> 6)][tid & 63] = fmaf(-ac[tid & 63], qb, ac[64 + (tid & 63)]);
  __syncthreads();

  // ---- phase 1: gather rows coalesced, compute h, store swizzled LDS bf16
  const int c = tid & 3;
#pragma unroll
  for (int pass = 0; pass < 4; ++pass) {
    const int r = (pass << 6) + (tid >> 2);
    const int pt = r >> 5;
    const int j = idxs[r];
    const float* up = u + ((bb + j) << 6);
    float4 uv[4];
#pragma unroll
    for (int i = 0; i < 4; ++i) uv[i] = *(const float4*)(up + (i << 4) + (c << 2));
#pragma unroll
    for (int i = 0; i < 4; ++i) {
      const int ch0 = (i << 4) + (c << 2);
      const f32x4 a = *(const f32x4*)&ac[ch0];
      const f32x4 rv = *(const f32x4*)&rs[pt][ch0];
      const float h0 = fmaxf(fmaf(a[0], uv[i].x, rv[0]), 0.f);
      const float h1 = fmaxf(fmaf(a[1], uv[i].y, rv[1]), 0.f);
      const float h2 = fmaxf(fmaf(a[2], uv[i].z, rv[2]), 0.f);
      const float h3 = fmaxf(fmaf(a[3], uv[i].w, rv[3]), 0.f);
      int byte = (r << 7) + (ch0 << 1);
      byte ^= (r & 7) << 4;
      *(uint2*)((char*)hl + byte) = make_uint2(pack_bf16(h0, h1), pack_bf16(h2, h3));
    }
  }

  bf16x8 bfr[8];
#pragma unroll
  for (int f = 0; f < 8; ++f)
    bfr[f] = __builtin_bit_cast(bf16x8, *(const uint4*)&w2frag[(f << 8) + (l << 2)]);
  __syncthreads();

  // ---- phase 2: per point: 16 MFMAs, stats
  float sm_[4] = {0.f, 0.f, 0.f, 0.f}, sq[4] = {0.f, 0.f, 0.f, 0.f};
#pragma unroll 1
  for (int pi = 0; pi < 2; ++pi) {
    const int ptl = (w << 1) + pi;
    const int pn = p0 + ptl;
    float mx[4], mn[4];
#pragma unroll
    for (int ot = 0; ot < 4; ++ot) { mx[ot] = -3e38f; mn[ot] = 3e38f; }
#pragma unroll
    for (int kt2 = 0; kt2 < 2; ++kt2) {
      bf16x8 afr[2];
#pragma unroll
      for (int kt = 0; kt < 2; ++kt) {
        const int srow = (ptl << 5) + (kt2 << 4) + (l & 15);
        int byte = (srow << 7) + (kt << 6) + ((l >> 4) << 4);
        byte ^= (srow & 7) << 4;
        afr[kt] = *(const bf16x8*)((const char*)hl + byte);
      }
#pragma unroll
      for (int ot = 0; ot < 4; ++ot) {
        f32x4 acc = {0.f, 0.f, 0.f, 0.f};
        acc = __builtin_amdgcn_mfma_f32_16x16x32_bf16(afr[0], bfr[ot], acc, 0, 0, 0);
        acc = __builtin_amdgcn_mfma_f32_16x16x32_bf16(afr[1], bfr[4 + ot], acc, 0, 0, 0);
#pragma unroll
        for (int e = 0; e < 4; ++e) {
          const float v = acc[e];
          mx[ot] = fmaxf(mx[ot], v); mn[ot] = fminf(mn[ot], v);
          sm_[ot] += v; sq[ot] = fmaf(v, v, sq[ot]);
        }
      }
    }
#pragma unroll
    for (int ot = 0; ot < 4; ++ot) {
      float a = fmaxf(mx[ot], __shfl_xor(mx[ot], 16)); a = fmaxf(a, __shfl_xor(a, 32));
      float b = fminf(mn[ot], __shfl_xor(mn[ot], 16)); b = fminf(b, __shfl_xor(b, 32));
      const int o = (ot << 4) + (l & 15);
      if (l < 16)      ymax[(pn << 6) + o] = a;
      else if (l < 32) ymin[(pn << 6) + o] = b;
    }
  }
#pragma unroll
  for (int ot = 0; ot < 4; ++ot) {
    float s = sm_[ot]; s += __shfl_xor(s, 16); s += __shfl_xor(s, 32);
    float t2 = sq[ot]; t2 += __shfl_xor(t2, 16); t2 += __shfl_xor(t2, 32);
    if (l < 16) { red[w][(ot << 4) + l] = s; red[4 + w][(ot << 4) + l] = t2; }
  }
  __syncthreads();
  if (tid < 128) {
    const int ch = tid & 63, sel = (tid >= 64) ? 4 : 0;
    const float v = red[sel][ch] + red[sel + 1][ch] + red[sel + 2][ch] + red[sel + 3][ch];
    atomicAdd(&part2b[((blk0 & 7) << 7) + tid], v);
  }
}

// ---------------- K4: output (inline a2c2 + LDS 64x64 transpose) ----------------
__global__ __launch_bounds__(256) void k_out(const float* __restrict__ ymax,
                                             const float* __restrict__ ymin,
                                             const float* __restrict__ part2b,
                                             const float* __restrict__ g2,
                                             const float* __restrict__ b2,
                                             float* __restrict__ out) {
  __shared__ float ac[128];
  __shared__ float tile[64][65];
  const int tid = threadIdx.x;
  if (tid < 64) {
    float s1 = 0.f, s2 = 0.f;
#pragma unroll
    for (int xx = 0; xx < 8; ++xx) {
      s1 += part2b[(xx << 7) + tid];
      s2 += part2b[(xx << 7) + 64 + tid];
    }
    const float mean = s1 * INVM, var = s2 * INVM - mean * mean;
    const float a = g2[tid] * rsqrtf(var + 1e-5f);
    ac[tid] = a; ac[64 + tid] = b2[tid] - mean * a;
  }
  __syncthreads();
  const int b = blockIdx.x >> 6, nt = blockIdx.x & 63;
  const int pnbase = (b << 12) + (nt << 6);
#pragma unroll
  for (int i = 0; i < 16; ++i) {
    const int e = i * 256 + tid;
    const int nl = e >> 6, o = e & 63;
    const float a = ac[o], c = ac[64 + o];
    const int src = ((pnbase + nl) << 6) + o;
    const float v = (a >= 0.f) ? ymax[src] : ymin[src];
    tile[nl][o] = fmaxf(fmaf(a, v, c), 0.f);
  }
  __syncthreads();
#pragma unroll
  for (int i = 0; i < 16; ++i) {
    const int e = i * 256 + tid;
    const int ol = e >> 6, nl = e & 63;
    out[(b << 18) + (ol << 12) + (nt << 6) + nl] = tile[nl][ol];
  }
}

extern "C" void kernel_launch(void* const* d_in, const int* in_sizes, int n_in,
                              void* d_out, int out_size, void* d_ws, size_t ws_size,
                              hipStream_t stream) {
  const float* p  = (const float*)d_in[0];
  const float* x  = (const float*)d_in[1];
  const float* W1 = (const float*)d_in[2];
  const float* g1 = (const float*)d_in[3];
  const float* b1 = (const float*)d_in[4];
  const float* W2 = (const float*)d_in[5];
  const float* g2 = (const float*)d_in[6];
  const float* b2 = (const float*)d_in[7];
  float* out = (float*)d_out;

  char* ws = (char*)d_ws;
  size_t off = 0;
  int* idx        = (int*)(ws + off);      off += 2097152;   // B*N*32 int
  float* u        = (float*)(ws + off);    off += 4194304;   // B*N*64 f32
  float* q        = (float*)(ws + off);    off += 4194304;
  uint32_t* w2f   = (uint32_t*)(ws + off); off += 8192;      // 8 frags * 64 lanes * 16B
  float* part1b   = (float*)(ws + off);    off += 4096;      // [8][128] XCD-private
  float* part2b   = (float*)(ws + off);    off += 4096;      // [8][128]
  float* ymax     = (float*)(ws + off);    off += 4194304;   // [pn][o]
  float* ymin     = (float*)(ws + off);    off += 4194304;   // ~18.9 MB total

  k_fused1<<<dim3(1153), dim3(1024), 0, stream>>>(p, x, W1, W2, idx, u, q, w2f,
                                                  part1b, part2b);
  k_bn1<<<dim3(1024), dim3(256), 0, stream>>>(u, q, idx, part1b);
  k_stage2<<<dim3(2048), dim3(256), 0, stream>>>(u, idx, q, part1b, g1, b1, w2f,
                                                 part2b, ymax, ymin);
  k_out<<<dim3(256), dim3(256), 0, stream>>>(ymax, ymin, part2b, g2, b2, out);
}